// Round 1
// baseline (658.854 us; speedup 1.0000x reference)
//
#include <hip/hip_runtime.h>
#include <float.h>

#define NC 64     // clusters
#define TI 64     // row tile
#define TJ 64     // col tile
#define LDA 68    // padded LDS leading dim (17*16B -> 16B aligned rows, bank spread)
#define LDB 68

// ---------------- prep: |x_i|^2 and label histogram ----------------
__global__ void prep_kernel(const float* __restrict__ feat,
                            const int* __restrict__ labels,
                            float* __restrict__ sq,
                            int* __restrict__ counts, int N) {
  __shared__ int hist[NC];
  int t = threadIdx.x;
  if (t < NC) hist[t] = 0;
  __syncthreads();
  int i = blockIdx.x * blockDim.x + t;
  if (i < N) {
    const float4* row = (const float4*)(feat + (size_t)i * 128);
    float s = 0.f;
#pragma unroll
    for (int k = 0; k < 32; ++k) {
      float4 v = row[k];
      s = fmaf(v.x, v.x, s); s = fmaf(v.y, v.y, s);
      s = fmaf(v.z, v.z, s); s = fmaf(v.w, v.w, s);
    }
    sq[i] = s;
    atomicAdd(&hist[labels[i]], 1);
  }
  __syncthreads();
  if (t < NC) atomicAdd(&counts[t], hist[t]);
}

// ---------------- main: tiled pairwise distances + segment-sum ----------------
// grid.x = row tiles (N/64), grid.y = column splits. Each block accumulates
// S_lds[row][cluster] = sum of dist(row, j) for j with label==cluster over its
// column range, then flushes to global S with atomics (or, FUSED, scores directly).
template <bool FUSED>
__global__ __launch_bounds__(256, 2)
void tile_kernel(const float* __restrict__ feat,
                 const int* __restrict__ labels,
                 const float* __restrict__ sq,
                 float* __restrict__ S_glob,
                 const int* __restrict__ counts,
                 float* __restrict__ out,
                 int N, int colsPerSplit) {
  __shared__ float Al[128 * LDA];   // k-major A tile  (34816 B)
  __shared__ float Bl[64 * LDB];    // k-major B stage (17408 B)
  __shared__ float Sl[TI * NC];     // per-row per-cluster sums (16384 B)
  __shared__ float sqj[TJ];
  __shared__ float sqi[TI];
  __shared__ int   labj[TJ];

  const int t = threadIdx.x;
  const int R = blockIdx.x * TI;
  const int colBegin = blockIdx.y * colsPerSplit;
  const int rg = t >> 4;   // 0..15 row group   (4 rows each)
  const int cg = t & 15;   // 0..15 col group   (4 cols each)

  for (int f = t; f < TI * NC; f += 256) Sl[f] = 0.f;

  // A tile (64 rows x 128 k), transposed into Al[k][r]. Loaded once per block.
#pragma unroll
  for (int it = 0; it < 8; ++it) {
    int f = t + 256 * it;          // 0..2047 float4s
    int r = f >> 5, k4 = f & 31;
    float4 v = *(const float4*)(feat + (size_t)(R + r) * 128 + k4 * 4);
    Al[(k4 * 4 + 0) * LDA + r] = v.x;
    Al[(k4 * 4 + 1) * LDA + r] = v.y;
    Al[(k4 * 4 + 2) * LDA + r] = v.z;
    Al[(k4 * 4 + 3) * LDA + r] = v.w;
  }
  if (t < TI) sqi[t] = sq[R + t];

  float acc[4][4];
#pragma unroll
  for (int r = 0; r < 4; ++r)
#pragma unroll
    for (int c = 0; c < 4; ++c) acc[r][c] = 0.f;

  const int numTiles = colsPerSplit / TJ;
  for (int ct = 0; ct < numTiles; ++ct) {
    const int cols = colBegin + ct * TJ;
#pragma unroll
    for (int s = 0; s < 2; ++s) {  // two 64-wide k stages to keep LDS <= 2 blocks/CU
      const int kk = s * 64;
      __syncthreads();             // prior compute/epilogue done before overwrite
#pragma unroll
      for (int it = 0; it < 4; ++it) {
        int f = t + 256 * it;      // 0..1023 float4s
        int c = f >> 4, k4 = f & 15;
        float4 v = *(const float4*)(feat + (size_t)(cols + c) * 128 + kk + k4 * 4);
        Bl[(k4 * 4 + 0) * LDB + c] = v.x;
        Bl[(k4 * 4 + 1) * LDB + c] = v.y;
        Bl[(k4 * 4 + 2) * LDB + c] = v.z;
        Bl[(k4 * 4 + 3) * LDB + c] = v.w;
      }
      if (s == 0 && t < TJ) {
        labj[t] = labels[cols + t];
        sqj[t]  = sq[cols + t];
      }
      __syncthreads();
#pragma unroll 8
      for (int k = 0; k < 64; ++k) {
        float4 av = *(const float4*)&Al[(kk + k) * LDA + rg * 4];
        float4 bv = *(const float4*)&Bl[k * LDB + cg * 4];
        float ar[4] = {av.x, av.y, av.z, av.w};
        float br[4] = {bv.x, bv.y, bv.z, bv.w};
#pragma unroll
        for (int r = 0; r < 4; ++r)
#pragma unroll
          for (int c = 0; c < 4; ++c)
            acc[r][c] = fmaf(ar[r], br[c], acc[r][c]);
      }
    }
    // epilogue: d2 -> dist -> scatter into Sl by column label
#pragma unroll
    for (int r = 0; r < 4; ++r) {
      float si = sqi[rg * 4 + r];
#pragma unroll
      for (int c = 0; c < 4; ++c) {
        float d2 = si + sqj[cg * 4 + c] - 2.f * acc[r][c];
        float dist = (d2 > 0.f) ? sqrtf(d2) : 0.f;  // grad-safe sqrt semantics
        atomicAdd(&Sl[(rg * 4 + r) * NC + labj[cg * 4 + c]], dist);
        acc[r][c] = 0.f;
      }
    }
  }
  __syncthreads();

  if (FUSED) {
    if (t < TI) {
      int gi = R + t;
      int li = labels[gi];
      float own = (float)counts[li];
      float a = Sl[t * NC + li] / fmaxf(own - 1.f, 1.f);
      float b = FLT_MAX;
#pragma unroll
      for (int c = 0; c < NC; ++c) {
        float cf = (float)counts[c];
        float m = Sl[t * NC + c] / fmaxf(cf, 1.f);
        bool invalid = (c == li) || (cf == 0.f);
        b = fminf(b, invalid ? FLT_MAX : m);
      }
      float mx = fmaxf(a, b);
      float score = (own > 1.f) ? (b - a) / mx : 0.f;
      atomicAdd(out, score / (float)N);
    }
  } else {
    // coalesced atomic flush: Sl is exactly rows [R, R+64) x NC, flat
    for (int f = t; f < TI * NC; f += 256)
      atomicAdd(&S_glob[(size_t)R * NC + f], Sl[f]);
  }
}

// ---------------- score: a, b, silhouette, mean ----------------
__global__ void score_kernel(const float* __restrict__ S,
                             const int* __restrict__ labels,
                             const int* __restrict__ counts,
                             float* __restrict__ out, int N) {
  __shared__ float cnt_s[NC];
  __shared__ float red[256];
  int t = threadIdx.x;
  if (t < NC) cnt_s[t] = (float)counts[t];
  __syncthreads();
  int i = blockIdx.x * 256 + t;
  float score = 0.f;
  if (i < N) {
    int li = labels[i];
    float own = cnt_s[li];
    const float* Si = S + (size_t)i * NC;
    float a = Si[li] / fmaxf(own - 1.f, 1.f);
    float b = FLT_MAX;
#pragma unroll
    for (int c = 0; c < NC; ++c) {
      float m = Si[c] / fmaxf(cnt_s[c], 1.f);
      bool invalid = (c == li) || (cnt_s[c] == 0.f);
      b = fminf(b, invalid ? FLT_MAX : m);
    }
    float mx = fmaxf(a, b);
    score = (own > 1.f) ? (b - a) / mx : 0.f;
  }
  red[t] = score;
  __syncthreads();
  for (int sft = 128; sft > 0; sft >>= 1) {
    if (t < sft) red[t] += red[t + sft];
    __syncthreads();
  }
  if (t == 0) atomicAdd(out, red[0] / (float)N);
}

extern "C" void kernel_launch(void* const* d_in, const int* in_sizes, int n_in,
                              void* d_out, int out_size, void* d_ws, size_t ws_size,
                              hipStream_t stream) {
  const float* feat  = (const float*)d_in[0];
  const int* labels  = (const int*)d_in[1];
  const int N = in_sizes[1];            // 8192; D fixed at 128, C fixed at 64
  float* out = (float*)d_out;
  char* ws = (char*)d_ws;

  int*   counts = (int*)ws;                                   // 64 ints
  float* sq     = (float*)(ws + 256);                         // N floats
  size_t offS   = 256 + (((size_t)N * 4 + 255) & ~(size_t)255);
  float* S      = (float*)(ws + offS);                        // N*64 floats
  size_t need   = offS + (size_t)N * NC * 4;
  bool fused    = ws_size < need;       // fallback if workspace too small

  hipMemsetAsync(counts, 0, 256, stream);
  hipMemsetAsync(d_out, 0, (size_t)out_size * sizeof(float), stream);
  if (!fused) hipMemsetAsync(S, 0, (size_t)N * NC * 4, stream);

  prep_kernel<<<(N + 255) / 256, 256, 0, stream>>>(feat, labels, sq, counts, N);

  if (!fused) {
    const int colSplit = 4;             // 512 blocks -> 2/CU across 256 CUs
    dim3 grid(N / TI, colSplit);
    tile_kernel<false><<<grid, 256, 0, stream>>>(feat, labels, sq, S, counts, out,
                                                 N, N / colSplit);
    score_kernel<<<(N + 255) / 256, 256, 0, stream>>>(S, labels, counts, out, N);
  } else {
    dim3 grid(N / TI, 1);
    tile_kernel<true><<<grid, 256, 0, stream>>>(feat, labels, sq, nullptr, counts, out,
                                                N, N);
  }
}

// Round 2
// 424.106 us; speedup vs baseline: 1.5535x; 1.5535x over previous
//
#include <hip/hip_runtime.h>
#include <float.h>

#define NC 64     // clusters
#define TI 128    // row tile
#define TJ 128    // col tile
#define KS 32     // k-slice
#define LDA 132   // padded LDS leading dims (132*4 % 16 == 0, breaks 8-way store conflicts)
#define LDB 132

// ---------------- prep: |x_i|^2 and label histogram ----------------
__global__ void prep_kernel(const float* __restrict__ feat,
                            const int* __restrict__ labels,
                            float* __restrict__ sq,
                            int* __restrict__ counts, int N) {
  __shared__ int hist[NC];
  int t = threadIdx.x;
  if (t < NC) hist[t] = 0;
  __syncthreads();
  int i = blockIdx.x * blockDim.x + t;
  if (i < N) {
    const float4* row = (const float4*)(feat + (size_t)i * 128);
    float s = 0.f;
#pragma unroll
    for (int k = 0; k < 32; ++k) {
      float4 v = row[k];
      s = fmaf(v.x, v.x, s); s = fmaf(v.y, v.y, s);
      s = fmaf(v.z, v.z, s); s = fmaf(v.w, v.w, s);
    }
    sq[i] = s;
    atomicAdd(&hist[labels[i]], 1);
  }
  __syncthreads();
  if (t < NC) atomicAdd(&counts[t], hist[t]);
}

// ---------------- exclusive prefix over 64 counts ----------------
__global__ void prefix_kernel(const int* __restrict__ counts,
                              int* __restrict__ offsets) {
  if (threadIdx.x == 0) {
    int acc = 0;
    for (int c = 0; c < NC; ++c) { offsets[c] = acc; acc += counts[c]; }
    offsets[NC] = acc;
  }
}

// ---------------- counting-sort scatter: columns grouped by label ----------------
__global__ void scatter_kernel(const int* __restrict__ labels,
                               const int* __restrict__ offsets,
                               int* __restrict__ cursor,
                               int* __restrict__ sIdx, int* __restrict__ sLab, int N) {
  int i = blockIdx.x * 256 + threadIdx.x;
  if (i < N) {
    int l = labels[i];
    int pos = offsets[l] + atomicAdd(&cursor[l], 1);
    sIdx[pos] = i;
    sLab[pos] = l;
  }
}

// ---------------- main: 128x128 tiles, 8x8 micro-tile, segment-sum ----------------
// MODE 0: label-sorted columns, shfl segment-reduce, flush to global S.
// MODE 1: natural columns, LDS atomic scatter, flush to global S.   (ws fallback)
// MODE 2: natural columns, atomic scatter, fused scoring (no S).    (ws fallback)
template <int MODE>
__global__ __launch_bounds__(256, 2)
void tile_kernel(const float* __restrict__ feat,
                 const int* __restrict__ labels,
                 const float* __restrict__ sq,
                 const int* __restrict__ sIdx,
                 const int* __restrict__ sLab,
                 const int* __restrict__ offsets,
                 const int* __restrict__ counts,
                 float* __restrict__ S_glob,
                 float* __restrict__ out,
                 int N, int colsPerSplit) {
  __shared__ float Al[KS * LDA];    // k-major A slice (16896 B)
  __shared__ float Bl[KS * LDB];    // k-major B slice (16896 B)
  __shared__ float Sl[TI * NC];     // per-row per-cluster sums (32768 B)
  __shared__ float sqi[TI], sqj[TJ];
  __shared__ int   labj[TJ], orig[TJ];
  __shared__ int   offs[NC + 1];

  const int t = threadIdx.x;
  const int R = blockIdx.x * TI;
  const int colBase0 = blockIdx.y * colsPerSplit;
  const int rg = t >> 4;    // 0..15, 8 rows each
  const int cg = t & 15;    // 0..15, 8 cols each

  for (int f = t; f < TI * NC; f += 256) Sl[f] = 0.f;
  if (t < TI) sqi[t] = sq[R + t];
  if (MODE == 0 && t <= NC) offs[t] = offsets[t];

  const int numTiles = colsPerSplit / TJ;
  for (int ct = 0; ct < numTiles; ++ct) {
    const int colBase = colBase0 + ct * TJ;
    __syncthreads();                     // prev epilogue done before metadata overwrite
    if (t < TJ) {
      int g, l;
      if (MODE == 0) { g = sIdx[colBase + t]; l = sLab[colBase + t]; }
      else           { g = colBase + t;       l = labels[g]; }
      orig[t] = g; labj[t] = l; sqj[t] = sq[g];
    }

    float acc[8][8];
#pragma unroll
    for (int r = 0; r < 8; ++r)
#pragma unroll
      for (int c = 0; c < 8; ++c) acc[r][c] = 0.f;

    for (int ks = 0; ks < 128 / KS; ++ks) {
      __syncthreads();                   // prev compute done / metadata visible
      // A slice: 128 rows x 32 k = 1024 float4s, transposed into Al[k][r]
#pragma unroll
      for (int it = 0; it < 4; ++it) {
        int f = t + 256 * it;
        int r = f >> 3, k4 = f & 7;
        float4 v = *(const float4*)(feat + (size_t)(R + r) * 128 + ks * KS + k4 * 4);
        Al[(k4 * 4 + 0) * LDA + r] = v.x;
        Al[(k4 * 4 + 1) * LDA + r] = v.y;
        Al[(k4 * 4 + 2) * LDA + r] = v.z;
        Al[(k4 * 4 + 3) * LDA + r] = v.w;
      }
      // B slice: gathered by sorted index
#pragma unroll
      for (int it = 0; it < 4; ++it) {
        int f = t + 256 * it;
        int c = f >> 3, k4 = f & 7;
        float4 v = *(const float4*)(feat + (size_t)orig[c] * 128 + ks * KS + k4 * 4);
        Bl[(k4 * 4 + 0) * LDB + c] = v.x;
        Bl[(k4 * 4 + 1) * LDB + c] = v.y;
        Bl[(k4 * 4 + 2) * LDB + c] = v.z;
        Bl[(k4 * 4 + 3) * LDB + c] = v.w;
      }
      __syncthreads();
#pragma unroll
      for (int k = 0; k < KS; ++k) {
        float4 a0 = *(const float4*)&Al[k * LDA + rg * 8];
        float4 a1 = *(const float4*)&Al[k * LDA + rg * 8 + 4];
        float4 b0 = *(const float4*)&Bl[k * LDB + cg * 8];
        float4 b1 = *(const float4*)&Bl[k * LDB + cg * 8 + 4];
        float av[8] = {a0.x, a0.y, a0.z, a0.w, a1.x, a1.y, a1.z, a1.w};
        float bv[8] = {b0.x, b0.y, b0.z, b0.w, b1.x, b1.y, b1.z, b1.w};
#pragma unroll
        for (int r = 0; r < 8; ++r)
#pragma unroll
          for (int c = 0; c < 8; ++c)
            acc[r][c] = fmaf(av[r], bv[c], acc[r][c]);
      }
    }

    // epilogue: d2 -> dist (grad-safe), zero diagonal
#pragma unroll
    for (int r = 0; r < 8; ++r) {
      float si = sqi[rg * 8 + r];
      int grow = R + rg * 8 + r;
#pragma unroll
      for (int c = 0; c < 8; ++c) {
        int cc = cg * 8 + c;
        float d2 = fmaf(-2.f, acc[r][c], si + sqj[cc]);
        float dist = (d2 > 0.f) ? sqrtf(d2) : 0.f;
        if (orig[cc] == grow) dist = 0.f;   // exact-zero self distance
        acc[r][c] = dist;
      }
    }

    if (MODE == 0) {
      // sorted columns: tile spans labels [labj[0], labj[127]] contiguously;
      // segment boundaries come from global cluster offsets. ~2 segments/tile.
      int l0 = labj[0], l1 = labj[TJ - 1];
      for (int L = l0; L <= l1; ++L) {
        int s = offs[L] - colBase;     if (s < 0) s = 0;
        int e = offs[L + 1] - colBase; if (e > TJ) e = TJ;
        if (s >= e) continue;
#pragma unroll
        for (int r = 0; r < 8; ++r) {
          float p = 0.f;
#pragma unroll
          for (int c = 0; c < 8; ++c) {
            int cc = cg * 8 + c;
            p += (cc >= s && cc < e) ? acc[r][c] : 0.f;
          }
          p += __shfl_xor(p, 1);
          p += __shfl_xor(p, 2);
          p += __shfl_xor(p, 4);
          p += __shfl_xor(p, 8);
          if (cg == 0) Sl[(rg * 8 + r) * NC + L] += p;  // unique (row,L) writer: raceless
        }
      }
    } else {
#pragma unroll
      for (int r = 0; r < 8; ++r)
#pragma unroll
        for (int c = 0; c < 8; ++c) {
          float d = acc[r][c];
          if (d != 0.f) atomicAdd(&Sl[(rg * 8 + r) * NC + labj[cg * 8 + c]], d);
        }
    }
  }
  __syncthreads();

  if (MODE == 2) {
    if (t < TI) {
      int gi = R + t;
      int li = labels[gi];
      float own = (float)counts[li];
      float a = Sl[t * NC + li] / fmaxf(own - 1.f, 1.f);
      float b = FLT_MAX;
#pragma unroll
      for (int c = 0; c < NC; ++c) {
        float cf = (float)counts[c];
        float m = Sl[t * NC + c] / fmaxf(cf, 1.f);
        bool invalid = (c == li) || (cf == 0.f);
        b = fminf(b, invalid ? FLT_MAX : m);
      }
      float mx = fmaxf(a, b);
      float score = (own > 1.f) ? (b - a) / mx : 0.f;
      atomicAdd(out, score / (float)N);
    }
  } else {
    for (int f = t; f < TI * NC; f += 256)
      atomicAdd(&S_glob[(size_t)R * NC + f], Sl[f]);
  }
}

// ---------------- score: a, b, silhouette, mean ----------------
__global__ void score_kernel(const float* __restrict__ S,
                             const int* __restrict__ labels,
                             const int* __restrict__ counts,
                             float* __restrict__ out, int N) {
  __shared__ float cnt_s[NC];
  __shared__ float red[256];
  int t = threadIdx.x;
  if (t < NC) cnt_s[t] = (float)counts[t];
  __syncthreads();
  int i = blockIdx.x * 256 + t;
  float score = 0.f;
  if (i < N) {
    int li = labels[i];
    float own = cnt_s[li];
    const float* Si = S + (size_t)i * NC;
    float a = Si[li] / fmaxf(own - 1.f, 1.f);
    float b = FLT_MAX;
#pragma unroll
    for (int c = 0; c < NC; ++c) {
      float m = Si[c] / fmaxf(cnt_s[c], 1.f);
      bool invalid = (c == li) || (cnt_s[c] == 0.f);
      b = fminf(b, invalid ? FLT_MAX : m);
    }
    float mx = fmaxf(a, b);
    score = (own > 1.f) ? (b - a) / mx : 0.f;
  }
  red[t] = score;
  __syncthreads();
  for (int sft = 128; sft > 0; sft >>= 1) {
    if (t < sft) red[t] += red[t + sft];
    __syncthreads();
  }
  if (t == 0) atomicAdd(out, red[0] / (float)N);
}

extern "C" void kernel_launch(void* const* d_in, const int* in_sizes, int n_in,
                              void* d_out, int out_size, void* d_ws, size_t ws_size,
                              hipStream_t stream) {
  const float* feat = (const float*)d_in[0];
  const int* labels = (const int*)d_in[1];
  const int N = in_sizes[1];            // 8192; D=128, C=64 fixed by the reference
  float* out = (float*)d_out;
  char* ws = (char*)d_ws;

  int*   counts  = (int*)ws;                    // 256 B
  int*   cursor  = (int*)(ws + 256);            // 256 B
  int*   offsets = (int*)(ws + 512);            // 512 B (65 ints)
  float* sq      = (float*)(ws + 1024);         // N*4
  size_t o = 1024 + (size_t)N * 4;
  int* sIdx = (int*)(ws + o);
  int* sLab = (int*)(ws + o + (size_t)N * 4);
  float* S_sorted = (float*)(ws + o + (size_t)N * 8);   // N*NC*4
  float* S_unsorted = (float*)(ws + o);                 // reuse sort space
  size_t need_sorted   = o + (size_t)N * 8 + (size_t)N * NC * 4;
  size_t need_unsorted = o + (size_t)N * NC * 4;

  int mode = (ws_size >= need_sorted) ? 0 : (ws_size >= need_unsorted) ? 1 : 2;
  float* S = (mode == 0) ? S_sorted : S_unsorted;

  hipMemsetAsync(ws, 0, 1024, stream);   // counts + cursor (+offsets, harmless)
  hipMemsetAsync(d_out, 0, (size_t)out_size * sizeof(float), stream);
  if (mode != 2) hipMemsetAsync(S, 0, (size_t)N * NC * 4, stream);

  prep_kernel<<<(N + 255) / 256, 256, 0, stream>>>(feat, labels, sq, counts, N);

  if (mode == 0) {
    prefix_kernel<<<1, 64, 0, stream>>>(counts, offsets);
    scatter_kernel<<<(N + 255) / 256, 256, 0, stream>>>(labels, offsets, cursor,
                                                        sIdx, sLab, N);
    const int colSplit = 8;              // 64 x 8 = 512 blocks -> 2/CU
    dim3 grid(N / TI, colSplit);
    tile_kernel<0><<<grid, 256, 0, stream>>>(feat, labels, sq, sIdx, sLab, offsets,
                                             counts, S, out, N, N / colSplit);
    score_kernel<<<(N + 255) / 256, 256, 0, stream>>>(S, labels, counts, out, N);
  } else if (mode == 1) {
    const int colSplit = 8;
    dim3 grid(N / TI, colSplit);
    tile_kernel<1><<<grid, 256, 0, stream>>>(feat, labels, sq, nullptr, nullptr, nullptr,
                                             counts, S, out, N, N / colSplit);
    score_kernel<<<(N + 255) / 256, 256, 0, stream>>>(S, labels, counts, out, N);
  } else {
    dim3 grid(N / TI, 1);
    tile_kernel<2><<<grid, 256, 0, stream>>>(feat, labels, sq, nullptr, nullptr, nullptr,
                                             counts, nullptr, out, N, N);
  }
}

// Round 3
// 349.504 us; speedup vs baseline: 1.8851x; 1.2135x over previous
//
#include <hip/hip_runtime.h>
#include <float.h>

#define NC 64     // clusters
#define FD 128    // feature dim

typedef __attribute__((ext_vector_type(8))) short bf16x8;   // 8 bf16 (4 VGPRs)
typedef __attribute__((ext_vector_type(4))) float f32x4;    // MFMA accumulator

// ---------------- prep: |x_i|^2 and label histogram ----------------
__global__ void prep_kernel(const float* __restrict__ feat,
                            const int* __restrict__ labels,
                            float* __restrict__ sq,
                            int* __restrict__ counts, int N) {
  __shared__ int hist[NC];
  int t = threadIdx.x;
  if (t < NC) hist[t] = 0;
  __syncthreads();
  int i = blockIdx.x * blockDim.x + t;
  if (i < N) {
    const float4* row = (const float4*)(feat + (size_t)i * FD);
    float s = 0.f;
#pragma unroll
    for (int k = 0; k < 32; ++k) {
      float4 v = row[k];
      s = fmaf(v.x, v.x, s); s = fmaf(v.y, v.y, s);
      s = fmaf(v.z, v.z, s); s = fmaf(v.w, v.w, s);
    }
    sq[i] = s;
    atomicAdd(&hist[labels[i]], 1);
  }
  __syncthreads();
  if (t < NC) atomicAdd(&counts[t], hist[t]);
}

// ---------------- exclusive prefix over 64 counts ----------------
__global__ void prefix_kernel(const int* __restrict__ counts,
                              int* __restrict__ offsets) {
  if (threadIdx.x == 0) {
    int acc = 0;
    for (int c = 0; c < NC; ++c) { offsets[c] = acc; acc += counts[c]; }
    offsets[NC] = acc;
  }
}

// ---------------- counting-sort scatter ----------------
__global__ void scatter_kernel(const int* __restrict__ labels,
                               const float* __restrict__ sq,
                               const int* __restrict__ offsets,
                               int* __restrict__ cursor,
                               int* __restrict__ sIdx, int* __restrict__ sLab,
                               float* __restrict__ sqs, int N) {
  int i = blockIdx.x * 256 + threadIdx.x;
  if (i < N) {
    int l = labels[i];
    int pos = offsets[l] + atomicAdd(&cursor[l], 1);
    sIdx[pos] = i;
    sLab[pos] = l;
    sqs[pos] = sq[i];
  }
}

// ---------------- split fp32 -> (hi, mid) bf16, gathered into sorted order ----
__device__ inline unsigned short bf16_rne(float f) {
  unsigned u = __float_as_uint(f);
  unsigned r = u + 0x7FFFu + ((u >> 16) & 1u);
  return (unsigned short)(r >> 16);
}

__global__ void split_kernel(const float* __restrict__ feat,
                             const int* __restrict__ sIdx,
                             unsigned short* __restrict__ Xhi,
                             unsigned short* __restrict__ Xmid, int N) {
  int id = blockIdx.x * 256 + threadIdx.x;   // one float4 per thread
  if (id >= N * (FD / 4)) return;
  int pos = id >> 5, c4 = id & 31;
  int i = sIdx[pos];
  float4 v = *(const float4*)(feat + (size_t)i * FD + c4 * 4);
  ushort4 h, m;
  h.x = bf16_rne(v.x); h.y = bf16_rne(v.y); h.z = bf16_rne(v.z); h.w = bf16_rne(v.w);
  m.x = bf16_rne(v.x - __uint_as_float((unsigned)h.x << 16));
  m.y = bf16_rne(v.y - __uint_as_float((unsigned)h.y << 16));
  m.z = bf16_rne(v.z - __uint_as_float((unsigned)h.z << 16));
  m.w = bf16_rne(v.w - __uint_as_float((unsigned)h.w << 16));
  *(ushort4*)&Xhi [(size_t)pos * FD + c4 * 4] = h;
  *(ushort4*)&Xmid[(size_t)pos * FD + c4 * 4] = m;
}

// ---------------- main: 3-pass split-bf16 MFMA Gram + segment-sum ----------------
// Sorted domain throughout. A tile (128 rows) resident full-K; B tile (128 cols)
// staged full-K per col-tile. Wave tile 64x64 = 4x4 MFMAs of 16x16x32.
// LDS stride 136 bf16 (272 B) makes frag reads bank-conflict-optimal.
#define LSTR 136
__global__ __launch_bounds__(256, 1)
void mfma_tile_kernel(const unsigned short* __restrict__ Xhi,
                      const unsigned short* __restrict__ Xmid,
                      const float* __restrict__ sqs,
                      const int* __restrict__ sLab,
                      float* __restrict__ S,
                      int N, int colsPerSplit) {
  __shared__ __align__(16) unsigned short Ahi[128 * LSTR];
  __shared__ __align__(16) unsigned short Amid[128 * LSTR];
  __shared__ __align__(16) unsigned short Bhi[128 * LSTR];
  __shared__ __align__(16) unsigned short Bmid[128 * LSTR];
  __shared__ float sqi[128], sqj[128];
  __shared__ int labj[128];

  const int t = threadIdx.x;
  const int R = blockIdx.x * 128;             // sorted row base
  const int cBeg = blockIdx.y * colsPerSplit;
  const int wave = t >> 6, lane = t & 63;
  const int wr = wave >> 1, wc = wave & 1;    // 2x2 wave grid
  const int m = lane & 15, quad = lane >> 4;

  // stage A (hi+mid), once per block: 128 rows x 128 k
#pragma unroll
  for (int it = 0; it < 8; ++it) {
    int c = t + it * 256;                     // 8-bf16 chunk id
    int r = c >> 4, k0 = (c & 15) * 8;
    *(uint4*)&Ahi [r * LSTR + k0] = *(const uint4*)&Xhi [(size_t)(R + r) * FD + k0];
    *(uint4*)&Amid[r * LSTR + k0] = *(const uint4*)&Xmid[(size_t)(R + r) * FD + k0];
  }
  if (t < 128) sqi[t] = sqs[R + t];

  const int numTiles = colsPerSplit / 128;
  for (int ct = 0; ct < numTiles; ++ct) {
    const int C0 = cBeg + ct * 128;
    __syncthreads();                          // prev compute done before B overwrite
#pragma unroll
    for (int it = 0; it < 8; ++it) {
      int c = t + it * 256;
      int r = c >> 4, k0 = (c & 15) * 8;
      *(uint4*)&Bhi [r * LSTR + k0] = *(const uint4*)&Xhi [(size_t)(C0 + r) * FD + k0];
      *(uint4*)&Bmid[r * LSTR + k0] = *(const uint4*)&Xmid[(size_t)(C0 + r) * FD + k0];
    }
    if (t < 128) { sqj[t] = sqs[C0 + t]; labj[t] = sLab[C0 + t]; }
    __syncthreads();

    f32x4 acc[4][4];
#pragma unroll
    for (int ib = 0; ib < 4; ++ib)
#pragma unroll
      for (int jb = 0; jb < 4; ++jb) acc[ib][jb] = (f32x4)0.f;

    // K loop: 4 steps of 32; per step 16 frag loads feed 48 MFMAs (3 passes share frags)
#pragma unroll
    for (int ks = 0; ks < 4; ++ks) {
      const int ko = ks * 32 + quad * 8;
      bf16x8 ah[4], am[4], bh[4], bm[4];
#pragma unroll
      for (int ib = 0; ib < 4; ++ib) {
        int row = wr * 64 + ib * 16 + m;
        ah[ib] = *(const bf16x8*)&Ahi [row * LSTR + ko];
        am[ib] = *(const bf16x8*)&Amid[row * LSTR + ko];
      }
#pragma unroll
      for (int jb = 0; jb < 4; ++jb) {
        int col = wc * 64 + jb * 16 + m;
        bh[jb] = *(const bf16x8*)&Bhi [col * LSTR + ko];
        bm[jb] = *(const bf16x8*)&Bmid[col * LSTR + ko];
      }
#pragma unroll
      for (int ib = 0; ib < 4; ++ib)
#pragma unroll
        for (int jb = 0; jb < 4; ++jb) {
          acc[ib][jb] = __builtin_amdgcn_mfma_f32_16x16x32_bf16(ah[ib], bh[jb], acc[ib][jb], 0, 0, 0);
          acc[ib][jb] = __builtin_amdgcn_mfma_f32_16x16x32_bf16(ah[ib], bm[jb], acc[ib][jb], 0, 0, 0);
          acc[ib][jb] = __builtin_amdgcn_mfma_f32_16x16x32_bf16(am[ib], bh[jb], acc[ib][jb], 0, 0, 0);
        }
    }

    // epilogue: d2 -> dist -> per-16-col label-segment reduce -> global atomics
#pragma unroll
    for (int ib = 0; ib < 4; ++ib) {
#pragma unroll
      for (int jb = 0; jb < 4; ++jb) {
        int c0 = wc * 64 + jb * 16;
        int lc = c0 + m;                      // this lane's column (C/D col = lane&15)
        int scol = C0 + lc;
        float sj = sqj[lc];
        int Lc = labj[lc];
        float v[4];
#pragma unroll
        for (int r = 0; r < 4; ++r) {         // C/D row = quad*4 + r
          int lr = wr * 64 + ib * 16 + quad * 4 + r;
          float d2 = fmaf(-2.f, acc[ib][jb][r], sqi[lr] + sj);
          float dist = (d2 > 0.f) ? sqrtf(d2) : 0.f;
          if (R + lr == scol) dist = 0.f;     // exact-zero self distance
          v[r] = dist;
        }
        int l0 = labj[c0], l1 = labj[c0 + 15];
        for (int L = l0; L <= l1; ++L) {
          bool in = (Lc == L);
          float v0 = in ? v[0] : 0.f, v1 = in ? v[1] : 0.f;
          float v2 = in ? v[2] : 0.f, v3 = in ? v[3] : 0.f;
          // 4-shfl multi-reduce: lane (m&3)==r ends with full 16-col sum of reg r
          bool o1 = (m & 1), o2 = (m & 2);
          float k01 = o1 ? v1 : v0, s01 = o1 ? v0 : v1;
          float k23 = o1 ? v3 : v2, s23 = o1 ? v2 : v3;
          float a01 = k01 + __shfl_xor(s01, 1);
          float a23 = k23 + __shfl_xor(s23, 1);
          float kb = o2 ? a23 : a01, sb = o2 ? a01 : a23;
          float b = kb + __shfl_xor(sb, 2);
          b += __shfl_xor(b, 4);
          b += __shfl_xor(b, 8);
          if (m < 4) {
            int lr = wr * 64 + ib * 16 + quad * 4 + m;
            atomicAdd(&S[(size_t)(R + lr) * NC + L], b);
          }
        }
      }
    }
  }
}

// ---------------- fallback fp32 tile kernel (round-2 MODE0) ----------------
#define TI 128
#define TJ 128
#define KS 32
#define LDA 132
#define LDB 132
__global__ __launch_bounds__(256, 2)
void tile_kernel_f32(const float* __restrict__ feat,
                     const float* __restrict__ sq,
                     const int* __restrict__ sIdx,
                     const int* __restrict__ sLab,
                     const int* __restrict__ offsets,
                     float* __restrict__ S_glob,
                     int N, int colsPerSplit) {
  __shared__ float Al[KS * LDA];
  __shared__ float Bl[KS * LDB];
  __shared__ float Sl[TI * NC];
  __shared__ float sqi[TI], sqj[TJ];
  __shared__ int   labj[TJ], orig[TJ];
  __shared__ int   offs[NC + 1];

  const int t = threadIdx.x;
  const int R = blockIdx.x * TI;
  const int colBase0 = blockIdx.y * colsPerSplit;
  const int rg = t >> 4, cg = t & 15;

  for (int f = t; f < TI * NC; f += 256) Sl[f] = 0.f;
  if (t < TI) sqi[t] = sq[sIdx[R + t]];
  if (t <= NC) offs[t] = offsets[t];

  const int numTiles = colsPerSplit / TJ;
  for (int ct = 0; ct < numTiles; ++ct) {
    const int colBase = colBase0 + ct * TJ;
    __syncthreads();
    if (t < TJ) {
      int g = sIdx[colBase + t];
      orig[t] = g; labj[t] = sLab[colBase + t]; sqj[t] = sq[g];
    }
    float acc[8][8];
#pragma unroll
    for (int r = 0; r < 8; ++r)
#pragma unroll
      for (int c = 0; c < 8; ++c) acc[r][c] = 0.f;

    for (int ks = 0; ks < FD / KS; ++ks) {
      __syncthreads();
#pragma unroll
      for (int it = 0; it < 4; ++it) {
        int f = t + 256 * it;
        int r = f >> 3, k4 = f & 7;
        float4 v = *(const float4*)(feat + (size_t)sIdx[R + r] * FD + ks * KS + k4 * 4);
        Al[(k4 * 4 + 0) * LDA + r] = v.x;
        Al[(k4 * 4 + 1) * LDA + r] = v.y;
        Al[(k4 * 4 + 2) * LDA + r] = v.z;
        Al[(k4 * 4 + 3) * LDA + r] = v.w;
      }
#pragma unroll
      for (int it = 0; it < 4; ++it) {
        int f = t + 256 * it;
        int c = f >> 3, k4 = f & 7;
        float4 v = *(const float4*)(feat + (size_t)orig[c] * FD + ks * KS + k4 * 4);
        Bl[(k4 * 4 + 0) * LDB + c] = v.x;
        Bl[(k4 * 4 + 1) * LDB + c] = v.y;
        Bl[(k4 * 4 + 2) * LDB + c] = v.z;
        Bl[(k4 * 4 + 3) * LDB + c] = v.w;
      }
      __syncthreads();
#pragma unroll
      for (int k = 0; k < KS; ++k) {
        float4 a0 = *(const float4*)&Al[k * LDA + rg * 8];
        float4 a1 = *(const float4*)&Al[k * LDA + rg * 8 + 4];
        float4 b0 = *(const float4*)&Bl[k * LDB + cg * 8];
        float4 b1 = *(const float4*)&Bl[k * LDB + cg * 8 + 4];
        float av[8] = {a0.x, a0.y, a0.z, a0.w, a1.x, a1.y, a1.z, a1.w};
        float bv[8] = {b0.x, b0.y, b0.z, b0.w, b1.x, b1.y, b1.z, b1.w};
#pragma unroll
        for (int r = 0; r < 8; ++r)
#pragma unroll
          for (int c = 0; c < 8; ++c)
            acc[r][c] = fmaf(av[r], bv[c], acc[r][c]);
      }
    }
#pragma unroll
    for (int r = 0; r < 8; ++r) {
      float si = sqi[rg * 8 + r];
      int grow = sIdx[R + rg * 8 + r];
#pragma unroll
      for (int c = 0; c < 8; ++c) {
        int cc = cg * 8 + c;
        float d2 = fmaf(-2.f, acc[r][c], si + sqj[cc]);
        float dist = (d2 > 0.f) ? sqrtf(d2) : 0.f;
        if (orig[cc] == grow) dist = 0.f;
        acc[r][c] = dist;
      }
    }
    int l0 = labj[0], l1 = labj[TJ - 1];
    for (int L = l0; L <= l1; ++L) {
      int s = offs[L] - colBase;     if (s < 0) s = 0;
      int e = offs[L + 1] - colBase; if (e > TJ) e = TJ;
      if (s >= e) continue;
#pragma unroll
      for (int r = 0; r < 8; ++r) {
        float p = 0.f;
#pragma unroll
        for (int c = 0; c < 8; ++c) {
          int cc = cg * 8 + c;
          p += (cc >= s && cc < e) ? acc[r][c] : 0.f;
        }
        p += __shfl_xor(p, 1);
        p += __shfl_xor(p, 2);
        p += __shfl_xor(p, 4);
        p += __shfl_xor(p, 8);
        if (cg == 0) Sl[(rg * 8 + r) * NC + L] += p;
      }
    }
  }
  __syncthreads();
  for (int f = t; f < TI * NC; f += 256)
    atomicAdd(&S_glob[(size_t)R * NC + f], Sl[f]);
}

// ---------------- score: a, b, silhouette, mean (labels in row order of S) ----
__global__ void score_kernel(const float* __restrict__ S,
                             const int* __restrict__ rowLab,
                             const int* __restrict__ counts,
                             float* __restrict__ out, int N) {
  __shared__ float cnt_s[NC];
  __shared__ float red[256];
  int t = threadIdx.x;
  if (t < NC) cnt_s[t] = (float)counts[t];
  __syncthreads();
  int i = blockIdx.x * 256 + t;
  float score = 0.f;
  if (i < N) {
    int li = rowLab[i];
    float own = cnt_s[li];
    const float* Si = S + (size_t)i * NC;
    float a = Si[li] / fmaxf(own - 1.f, 1.f);
    float b = FLT_MAX;
#pragma unroll
    for (int c = 0; c < NC; ++c) {
      float mm = Si[c] / fmaxf(cnt_s[c], 1.f);
      bool invalid = (c == li) || (cnt_s[c] == 0.f);
      b = fminf(b, invalid ? FLT_MAX : mm);
    }
    float mx = fmaxf(a, b);
    score = (own > 1.f) ? (b - a) / mx : 0.f;
  }
  red[t] = score;
  __syncthreads();
  for (int sft = 128; sft > 0; sft >>= 1) {
    if (t < sft) red[t] += red[t + sft];
    __syncthreads();
  }
  if (t == 0) atomicAdd(out, red[0] / (float)N);
}

extern "C" void kernel_launch(void* const* d_in, const int* in_sizes, int n_in,
                              void* d_out, int out_size, void* d_ws, size_t ws_size,
                              hipStream_t stream) {
  const float* feat = (const float*)d_in[0];
  const int* labels = (const int*)d_in[1];
  const int N = in_sizes[1];            // 8192; D=128, C=64 fixed by the reference
  float* out = (float*)d_out;
  char* ws = (char*)d_ws;

  // workspace layout
  int*   counts  = (int*)ws;                          // 256 B
  int*   cursor  = (int*)(ws + 256);                  // 256 B
  int*   offsets = (int*)(ws + 512);                  // 512 B
  float* sq      = (float*)(ws + 1024);               // N*4
  size_t o = 1024 + (size_t)N * 4;
  int*   sIdx = (int*)(ws + o);                       // N*4
  int*   sLab = (int*)(ws + o + (size_t)N * 4);       // N*4
  float* sqs  = (float*)(ws + o + (size_t)N * 8);     // N*4
  size_t oX = o + (size_t)N * 12;
  oX = (oX + 255) & ~(size_t)255;
  unsigned short* Xhi  = (unsigned short*)(ws + oX);                      // N*128*2
  unsigned short* Xmid = (unsigned short*)(ws + oX + (size_t)N * FD * 2); // N*128*2
  float* S = (float*)(ws + oX + (size_t)N * FD * 4);                      // N*64*4
  size_t need_mfma = oX + (size_t)N * FD * 4 + (size_t)N * NC * 4;
  size_t need_f32  = o + (size_t)N * 12 + (size_t)N * NC * 4;
  float* S_f32 = (float*)(ws + o + (size_t)N * 12);

  bool use_mfma = (ws_size >= need_mfma) && (N % 256 == 0);
  float* Suse = use_mfma ? S : S_f32;

  hipMemsetAsync(ws, 0, 1024, stream);
  hipMemsetAsync(d_out, 0, (size_t)out_size * sizeof(float), stream);
  hipMemsetAsync(Suse, 0, (size_t)N * NC * 4, stream);

  prep_kernel<<<(N + 255) / 256, 256, 0, stream>>>(feat, labels, sq, counts, N);
  prefix_kernel<<<1, 64, 0, stream>>>(counts, offsets);
  scatter_kernel<<<(N + 255) / 256, 256, 0, stream>>>(labels, sq, offsets, cursor,
                                                      sIdx, sLab, sqs, N);

  if (use_mfma) {
    split_kernel<<<(N * (FD / 4) + 255) / 256, 256, 0, stream>>>(feat, sIdx, Xhi, Xmid, N);
    const int colSplit = 4;              // 64 x 4 = 256 blocks = 1/CU
    dim3 grid(N / 128, colSplit);
    mfma_tile_kernel<<<grid, 256, 0, stream>>>(Xhi, Xmid, sqs, sLab, S,
                                               N, N / colSplit);
    score_kernel<<<(N + 255) / 256, 256, 0, stream>>>(S, sLab, counts, out, N);
  } else {
    const int colSplit = 8;
    dim3 grid(N / TI, colSplit);
    tile_kernel_f32<<<grid, 256, 0, stream>>>(feat, sq, sIdx, sLab, offsets,
                                              S_f32, N, N / colSplit);
    score_kernel<<<(N + 255) / 256, 256, 0, stream>>>(S_f32, sLab, counts, out, N);
  }
}

// Round 4
// 204.345 us; speedup vs baseline: 3.2242x; 1.7104x over previous
//
#include <hip/hip_runtime.h>
#include <float.h>

#define NC 64     // clusters
#define FD 128    // feature dim
#define LSTR 136  // LDS row stride in bf16 (pad 8: 68 words/row, 68%32=4 -> 2-way max, free)

typedef __attribute__((ext_vector_type(8))) short bf16x8;   // 8 bf16 (4 VGPRs)
typedef __attribute__((ext_vector_type(4))) float f32x4;    // MFMA accumulator

__device__ inline unsigned short bf16_rne(float f) {
  unsigned u = __float_as_uint(f);
  unsigned r = u + 0x7FFFu + ((u >> 16) & 1u);
  return (unsigned short)(r >> 16);
}
__device__ inline float bf16_f(unsigned short h) {
  return __uint_as_float((unsigned)h << 16);
}

// ---------------- prep: |x|^2, bf16 hi/mid split, label histogram ----------------
// 8 lanes per row (coalesced 128B groups), 32 rows per 256-thread block.
__global__ void prep_kernel(const float* __restrict__ feat,
                            const int* __restrict__ labels,
                            float* __restrict__ sq,
                            unsigned short* __restrict__ Xhi,
                            unsigned short* __restrict__ Xmid,
                            int* __restrict__ counts, int N) {
  __shared__ int hist[NC];
  int t = threadIdx.x;
  if (t < NC) hist[t] = 0;
  __syncthreads();
  int row = blockIdx.x * 32 + (t >> 3);
  int o = t & 7;
  if (row < N) {
    const float* rp = feat + (size_t)row * FD;
    float s = 0.f;
#pragma unroll
    for (int j = 0; j < 4; ++j) {
      int c4 = o + 8 * j;
      float4 v = *(const float4*)(rp + c4 * 4);
      ushort4 h, mm;
      h.x = bf16_rne(v.x); h.y = bf16_rne(v.y); h.z = bf16_rne(v.z); h.w = bf16_rne(v.w);
      mm.x = bf16_rne(v.x - bf16_f(h.x));
      mm.y = bf16_rne(v.y - bf16_f(h.y));
      mm.z = bf16_rne(v.z - bf16_f(h.z));
      mm.w = bf16_rne(v.w - bf16_f(h.w));
      *(ushort4*)&Xhi [(size_t)row * FD + c4 * 4] = h;
      *(ushort4*)&Xmid[(size_t)row * FD + c4 * 4] = mm;
      s = fmaf(v.x, v.x, s); s = fmaf(v.y, v.y, s);
      s = fmaf(v.z, v.z, s); s = fmaf(v.w, v.w, s);
    }
    s += __shfl_xor(s, 1); s += __shfl_xor(s, 2); s += __shfl_xor(s, 4);
    if (o == 0) { sq[row] = s; atomicAdd(&hist[labels[row]], 1); }
  }
  __syncthreads();
  if (t < NC) atomicAdd(&counts[t], hist[t]);
}

// ---------------- main: Dist = 3-pass split-bf16 MFMA; S_tile = Dist x M via MFMA ----
// 512 threads = 8 waves. Dist pass: 4x2 wave grid, wave tile 32x64.
// S pass: wave w owns rows [w*16, w*16+16), labels 0..63 in 4 tiles.
// Dh/Dm reuse the Bh/Bm LDS (B frags fully consumed before D writes).
__global__ __launch_bounds__(512, 1)
void mfma_tile_kernel(const unsigned short* __restrict__ Xhi,
                      const unsigned short* __restrict__ Xmid,
                      const float* __restrict__ sq,
                      const int* __restrict__ labels,
                      float* __restrict__ S,
                      int N, int colsPerSplit) {
  __shared__ __align__(16) unsigned short Ah[128 * LSTR];  // 34816 B
  __shared__ __align__(16) unsigned short Am[128 * LSTR];
  __shared__ __align__(16) unsigned short Bh[128 * LSTR];  // reused as Dh
  __shared__ __align__(16) unsigned short Bm[128 * LSTR];  // reused as Dm
  __shared__ __align__(16) unsigned short Mt[NC * LSTR];   // M^T[label][col], 17408 B
  __shared__ float sqi[128], sqj[128];
  __shared__ int labj[128];
  // total LDS: 4*34816 + 17408 + 1536 = 158 KB (1 block/CU)

  const int t = threadIdx.x;
  const int R = blockIdx.x * 128;
  const int cBeg = blockIdx.y * colsPerSplit;
  const int wave = t >> 6, lane = t & 63;
  const int m = lane & 15, quad = lane >> 4;
  const int wr = wave >> 1, wc = wave & 1;   // 4x2 wave grid over 128x128

  // stage A full-K (once per block): 2048 16B chunks over 512 threads
#pragma unroll
  for (int it = 0; it < 4; ++it) {
    int c = t + it * 512;
    int r = c >> 4, k0 = (c & 15) * 8;
    *(uint4*)&Ah[r * LSTR + k0] = *(const uint4*)&Xhi [(size_t)(R + r) * FD + k0];
    *(uint4*)&Am[r * LSTR + k0] = *(const uint4*)&Xmid[(size_t)(R + r) * FD + k0];
  }
  if (t < 128) sqi[t] = sq[R + t];

  f32x4 sacc[4];                             // S accumulators, persist across col-tiles
#pragma unroll
  for (int lt = 0; lt < 4; ++lt) sacc[lt] = (f32x4)0.f;

  const int numTiles = colsPerSplit / 128;
  for (int ct = 0; ct < numTiles; ++ct) {
    const int C0 = cBeg + ct * 128;
    __syncthreads();                         // prev S-pass done before B/Mt overwrite
#pragma unroll
    for (int it = 0; it < 4; ++it) {
      int c = t + it * 512;
      int r = c >> 4, k0 = (c & 15) * 8;
      *(uint4*)&Bh[r * LSTR + k0] = *(const uint4*)&Xhi [(size_t)(C0 + r) * FD + k0];
      *(uint4*)&Bm[r * LSTR + k0] = *(const uint4*)&Xmid[(size_t)(C0 + r) * FD + k0];
    }
    if (t < 128) { sqj[t] = sq[C0 + t]; labj[t] = labels[C0 + t]; }
    __syncthreads();                         // B, sqj, labj visible

    // build M^T for this col-tile: thread t fills label c=t>>3, cols [(t&7)*16, +16)
    {
      int c = t >> 3, j0 = (t & 7) * 16;
#pragma unroll
      for (int j = 0; j < 16; ++j)
        Mt[c * LSTR + j0 + j] =
            (labj[j0 + j] == c) ? (unsigned short)0x3F80 : (unsigned short)0;
    }

    // Dist pass: wave tile 32x64, 2x4 MFMAs of 16x16x32, 3 split passes
    f32x4 dacc[2][4];
#pragma unroll
    for (int ib = 0; ib < 2; ++ib)
#pragma unroll
      for (int jb = 0; jb < 4; ++jb) dacc[ib][jb] = (f32x4)0.f;

#pragma unroll
    for (int ks = 0; ks < 4; ++ks) {
      const int ko = ks * 32 + quad * 8;
      bf16x8 ah[2], am[2], bh[4], bm[4];
#pragma unroll
      for (int ib = 0; ib < 2; ++ib) {
        int row = wr * 32 + ib * 16 + m;
        ah[ib] = *(const bf16x8*)&Ah[row * LSTR + ko];
        am[ib] = *(const bf16x8*)&Am[row * LSTR + ko];
      }
#pragma unroll
      for (int jb = 0; jb < 4; ++jb) {
        int col = wc * 64 + jb * 16 + m;
        bh[jb] = *(const bf16x8*)&Bh[col * LSTR + ko];
        bm[jb] = *(const bf16x8*)&Bm[col * LSTR + ko];
      }
#pragma unroll
      for (int ib = 0; ib < 2; ++ib)
#pragma unroll
        for (int jb = 0; jb < 4; ++jb) {
          dacc[ib][jb] = __builtin_amdgcn_mfma_f32_16x16x32_bf16(ah[ib], bh[jb], dacc[ib][jb], 0, 0, 0);
          dacc[ib][jb] = __builtin_amdgcn_mfma_f32_16x16x32_bf16(ah[ib], bm[jb], dacc[ib][jb], 0, 0, 0);
          dacc[ib][jb] = __builtin_amdgcn_mfma_f32_16x16x32_bf16(am[ib], bh[jb], dacc[ib][jb], 0, 0, 0);
        }
    }
    __syncthreads();                         // all waves done reading B -> reuse as D

    // d2 -> dist (grad-safe, exact-zero diagonal), split hi/mid into Bh/Bm
#pragma unroll
    for (int ib = 0; ib < 2; ++ib)
#pragma unroll
      for (int jb = 0; jb < 4; ++jb) {
        int col = wc * 64 + jb * 16 + m;     // C/D col = lane&15
        float sj = sqj[col];
#pragma unroll
        for (int r = 0; r < 4; ++r) {        // C/D row = quad*4 + r
          int row = wr * 32 + ib * 16 + quad * 4 + r;
          float d2 = fmaf(-2.f, dacc[ib][jb][r], sqi[row] + sj);
          float dist = (d2 > 0.f) ? sqrtf(d2) : 0.f;
          if (R + row == C0 + col) dist = 0.f;
          unsigned short dh = bf16_rne(dist);
          Bh[row * LSTR + col] = dh;
          Bm[row * LSTR + col] = bf16_rne(dist - bf16_f(dh));
        }
      }
    __syncthreads();                         // D (and Mt) ready

    // S pass: S_tile[128x64] += D[128x128] x M[128x64], 2 split passes
#pragma unroll
    for (int ks = 0; ks < 4; ++ks) {
      const int ko = ks * 32 + quad * 8;
      int drow = wave * 16 + m;              // A-operand m-index = row
      bf16x8 da = *(const bf16x8*)&Bh[drow * LSTR + ko];
      bf16x8 dm = *(const bf16x8*)&Bm[drow * LSTR + ko];
#pragma unroll
      for (int lt = 0; lt < 4; ++lt) {
        bf16x8 mb = *(const bf16x8*)&Mt[(lt * 16 + m) * LSTR + ko];  // B[n][k], n=label
        sacc[lt] = __builtin_amdgcn_mfma_f32_16x16x32_bf16(da, mb, sacc[lt], 0, 0, 0);
        sacc[lt] = __builtin_amdgcn_mfma_f32_16x16x32_bf16(dm, mb, sacc[lt], 0, 0, 0);
      }
    }
  }

  // flush: one atomic per S entry; lanes m-consecutive -> coalesced label runs
#pragma unroll
  for (int lt = 0; lt < 4; ++lt)
#pragma unroll
    for (int r = 0; r < 4; ++r) {
      int row = wave * 16 + quad * 4 + r;
      atomicAdd(&S[(size_t)(R + row) * NC + lt * 16 + m], sacc[lt][r]);
    }
}

// ---------------- score: a, b, silhouette, mean ----------------
__global__ void score_kernel(const float* __restrict__ S,
                             const int* __restrict__ labels,
                             const int* __restrict__ counts,
                             float* __restrict__ out, int N) {
  __shared__ float cnt_s[NC];
  __shared__ float red[256];
  int t = threadIdx.x;
  if (t < NC) cnt_s[t] = (float)counts[t];
  __syncthreads();
  int i = blockIdx.x * 256 + t;
  float score = 0.f;
  if (i < N) {
    int li = labels[i];
    float own = cnt_s[li];
    const float* Si = S + (size_t)i * NC;
    float a = Si[li] / fmaxf(own - 1.f, 1.f);
    float b = FLT_MAX;
#pragma unroll
    for (int c = 0; c < NC; ++c) {
      float mm = Si[c] / fmaxf(cnt_s[c], 1.f);
      bool invalid = (c == li) || (cnt_s[c] == 0.f);
      b = fminf(b, invalid ? FLT_MAX : mm);
    }
    float mx = fmaxf(a, b);
    score = (own > 1.f) ? (b - a) / mx : 0.f;
  }
  red[t] = score;
  __syncthreads();
  for (int sft = 128; sft > 0; sft >>= 1) {
    if (t < sft) red[t] += red[t + sft];
    __syncthreads();
  }
  if (t == 0) atomicAdd(out, red[0] / (float)N);
}

extern "C" void kernel_launch(void* const* d_in, const int* in_sizes, int n_in,
                              void* d_out, int out_size, void* d_ws, size_t ws_size,
                              hipStream_t stream) {
  const float* feat = (const float*)d_in[0];
  const int* labels = (const int*)d_in[1];
  const int N = in_sizes[1];            // 8192; D=128, C=64 fixed by the reference
  float* out = (float*)d_out;
  char* ws = (char*)d_ws;

  // workspace: counts | sq | Xhi | Xmid | S   (~6.13 MB at N=8192; ws held >=6.4 MB)
  int*   counts = (int*)ws;                                  // 256 B
  float* sq     = (float*)(ws + 256);                        // N*4
  size_t o = 256 + (size_t)N * 4;
  o = (o + 255) & ~(size_t)255;
  unsigned short* Xhi  = (unsigned short*)(ws + o);                      // N*FD*2
  unsigned short* Xmid = (unsigned short*)(ws + o + (size_t)N * FD * 2); // N*FD*2
  float* S = (float*)(ws + o + (size_t)N * FD * 4);                      // N*NC*4

  hipMemsetAsync(counts, 0, 256, stream);
  hipMemsetAsync(d_out, 0, (size_t)out_size * sizeof(float), stream);
  hipMemsetAsync(S, 0, (size_t)N * NC * 4, stream);

  prep_kernel<<<(N + 31) / 32, 256, 0, stream>>>(feat, labels, sq, Xhi, Xmid, counts, N);

  const int colSplit = 4;               // 64 x 4 = 256 blocks = 1/CU (8 waves each)
  dim3 grid(N / 128, colSplit);
  mfma_tile_kernel<<<grid, 512, 0, stream>>>(Xhi, Xmid, sq, labels, S, N, N / colSplit);

  score_kernel<<<(N + 255) / 256, 256, 0, stream>>>(S, labels, counts, out, N);
}

// Round 5
// 173.615 us; speedup vs baseline: 3.7949x; 1.1770x over previous
//
#include <hip/hip_runtime.h>
#include <hip/hip_fp16.h>
#include <float.h>

#define NC 64     // clusters
#define FD 128    // feature dim
#define LSTR 136  // LDS row stride in halfs (pad 8 -> 68 dwords/row, 68%32=4: benign)

typedef _Float16 f16x8 __attribute__((ext_vector_type(8)));
typedef float f32x4 __attribute__((ext_vector_type(4)));

// ---------------- prep: fp16 cast, |x|^2, histogram, Mt build, S zero ----------------
__global__ void prep_kernel(const float* __restrict__ feat,
                            const int* __restrict__ labels,
                            float* __restrict__ sq,
                            unsigned short* __restrict__ Xh,
                            unsigned short* __restrict__ Mt,
                            float* __restrict__ S,
                            int* __restrict__ counts, int N) {
  __shared__ int hist[NC];
  int t = threadIdx.x;
  if (t < NC) hist[t] = 0;
  __syncthreads();
  int row = blockIdx.x * 32 + (t >> 3);
  int o = t & 7;
  if (row < N) {
    const float* rp = feat + (size_t)row * FD;
    float s = 0.f;
#pragma unroll
    for (int j = 0; j < 4; ++j) {
      int c4 = o + 8 * j;
      float4 v = *(const float4*)(rp + c4 * 4);
      ushort4 h;
      h.x = __half_as_ushort(__float2half(v.x));   // v_cvt_f16_f32: RNE
      h.y = __half_as_ushort(__float2half(v.y));
      h.z = __half_as_ushort(__float2half(v.z));
      h.w = __half_as_ushort(__float2half(v.w));
      *(ushort4*)&Xh[(size_t)row * FD + c4 * 4] = h;
      s = fmaf(v.x, v.x, s); s = fmaf(v.y, v.y, s);
      s = fmaf(v.z, v.z, s); s = fmaf(v.w, v.w, s);
    }
    s += __shfl_xor(s, 1); s += __shfl_xor(s, 2); s += __shfl_xor(s, 4);
    if (o == 0) { sq[row] = s; atomicAdd(&hist[labels[row]], 1); }
  }
  // zero S rows for this block (32 rows x NC floats = 8 floats/thread)
  if ((blockIdx.x + 1) * 32 <= N) {
    float4 z = {0.f, 0.f, 0.f, 0.f};
    size_t base = (size_t)blockIdx.x * 32 * NC + t * 8;
    *(float4*)&S[base] = z;
    *(float4*)&S[base + 4] = z;
  }
  // build Mt[n][col] = (labels[col]==n) ? 1.0h : 0  (8-col chunks)
  {
    int chunksPerN = N >> 3;
    int total = NC * chunksPerN;
    for (int id = blockIdx.x * 256 + t; id < total; id += gridDim.x * 256) {
      int n = id / chunksPerN;
      int c0 = (id - n * chunksPerN) * 8;
      ushort4 lo, hi;
      lo.x = (labels[c0 + 0] == n) ? 0x3C00 : 0;
      lo.y = (labels[c0 + 1] == n) ? 0x3C00 : 0;
      lo.z = (labels[c0 + 2] == n) ? 0x3C00 : 0;
      lo.w = (labels[c0 + 3] == n) ? 0x3C00 : 0;
      hi.x = (labels[c0 + 4] == n) ? 0x3C00 : 0;
      hi.y = (labels[c0 + 5] == n) ? 0x3C00 : 0;
      hi.z = (labels[c0 + 6] == n) ? 0x3C00 : 0;
      hi.w = (labels[c0 + 7] == n) ? 0x3C00 : 0;
      *(ushort4*)&Mt[(size_t)n * N + c0] = lo;
      *(ushort4*)&Mt[(size_t)n * N + c0 + 4] = hi;
    }
  }
  __syncthreads();
  if (t < NC) atomicAdd(&counts[t], hist[t]);
}

// ---------------- main: fp16 MFMA Gram (single pass) + MFMA segment-sum ----------------
// 256 threads = 4 waves in 2x2 grid, wave tile 64x64 over a 128x128 block tile.
// A resident full-K; B staged per col-tile, reused as D (fp16 dist) for the S-pass.
// S-pass B-operand (one-hot M) read directly from global Mt (L1/L2-resident).
// LDS = 2 x 34.8 KB -> 2 blocks/CU; their barriers interleave.
__global__ __launch_bounds__(256, 2)
void mfma_tile_kernel(const unsigned short* __restrict__ Xh,
                      const float* __restrict__ sq,
                      const unsigned short* __restrict__ Mt,
                      float* __restrict__ S,
                      int N, int colsPerSplit) {
  __shared__ __align__(16) unsigned short Ah[128 * LSTR];  // 34816 B
  __shared__ __align__(16) unsigned short Bh[128 * LSTR];  // 34816 B, reused as Dh

  const int t = threadIdx.x;
  const int R = blockIdx.x * 128;
  const int cBeg = blockIdx.y * colsPerSplit;
  const int wave = t >> 6, lane = t & 63;
  const int m = lane & 15, quad = lane >> 4;
  const int wr = wave >> 1, wc = wave & 1;   // 2x2 wave grid, 64x64 wave tiles

  // stage A full-K: 128 rows x 256B = 2048 x 16B chunks over 256 threads
#pragma unroll
  for (int it = 0; it < 8; ++it) {
    int c = t + it * 256;
    int r = c >> 4, k0 = (c & 15) * 8;
    *(uint4*)&Ah[r * LSTR + k0] = *(const uint4*)&Xh[(size_t)(R + r) * FD + k0];
  }

  // per-lane row |x|^2 (broadcast-friendly global loads, once per block)
  float sqi_r[4][4];
#pragma unroll
  for (int ib = 0; ib < 4; ++ib)
#pragma unroll
    for (int r = 0; r < 4; ++r)
      sqi_r[ib][r] = sq[R + wr * 64 + ib * 16 + quad * 4 + r];

  f32x4 sacc[2][4];                          // S accum: 2 row-tiles x 4 label-tiles
#pragma unroll
  for (int rt = 0; rt < 2; ++rt)
#pragma unroll
    for (int lt = 0; lt < 4; ++lt) sacc[rt][lt] = (f32x4)0.f;

  const int numTiles = colsPerSplit / 128;
  for (int ct = 0; ct < numTiles; ++ct) {
    const int C0 = cBeg + ct * 128;
    __syncthreads();                         // prev S-pass done before B overwrite
#pragma unroll
    for (int it = 0; it < 8; ++it) {
      int c = t + it * 256;
      int r = c >> 4, k0 = (c & 15) * 8;
      *(uint4*)&Bh[r * LSTR + k0] = *(const uint4*)&Xh[(size_t)(C0 + r) * FD + k0];
    }
    float sjr[4];
#pragma unroll
    for (int jb = 0; jb < 4; ++jb)
      sjr[jb] = sq[C0 + wc * 64 + jb * 16 + m];
    __syncthreads();

    // Dist pass: 4x4 MFMAs of 16x16x32_f16 per k-step, single fp16 pass
    f32x4 dacc[4][4];
#pragma unroll
    for (int ib = 0; ib < 4; ++ib)
#pragma unroll
      for (int jb = 0; jb < 4; ++jb) dacc[ib][jb] = (f32x4)0.f;

#pragma unroll
    for (int ks = 0; ks < 4; ++ks) {
      const int ko = ks * 32 + quad * 8;
      f16x8 af[4], bf[4];
#pragma unroll
      for (int ib = 0; ib < 4; ++ib)
        af[ib] = *(const f16x8*)&Ah[(wr * 64 + ib * 16 + m) * LSTR + ko];
#pragma unroll
      for (int jb = 0; jb < 4; ++jb)
        bf[jb] = *(const f16x8*)&Bh[(wc * 64 + jb * 16 + m) * LSTR + ko];
#pragma unroll
      for (int ib = 0; ib < 4; ++ib)
#pragma unroll
        for (int jb = 0; jb < 4; ++jb)
          dacc[ib][jb] = __builtin_amdgcn_mfma_f32_16x16x32_f16(af[ib], bf[jb], dacc[ib][jb], 0, 0, 0);
    }
    __syncthreads();                         // all waves done reading Bh -> reuse as Dh

    // epilogue: d2 -> dist (grad-safe, exact-zero diagonal) -> fp16 into Dh
    const bool hasDiag = (R == C0);          // both 128-aligned: diag only when equal
#pragma unroll
    for (int ib = 0; ib < 4; ++ib)
#pragma unroll
      for (int jb = 0; jb < 4; ++jb) {
        int col = wc * 64 + jb * 16 + m;     // C/D col = lane&15
        float sj = sjr[jb];
#pragma unroll
        for (int r = 0; r < 4; ++r) {        // C/D row = quad*4 + r
          int row = wr * 64 + ib * 16 + quad * 4 + r;
          float d2 = fmaf(-2.f, dacc[ib][jb][r], sqi_r[ib][r] + sj);
          float dist = (d2 > 0.f) ? sqrtf(d2) : 0.f;
          if (hasDiag && row == col) dist = 0.f;
          Bh[row * LSTR + col] = __half_as_ushort(__float2half(dist));
        }
      }
    __syncthreads();                         // Dh ready

    // S-pass: S_tile[128xNC] += D[128x128] x M[128xNC]; M frags from global Mt
#pragma unroll
    for (int ks = 0; ks < 4; ++ks) {
      const int ko = ks * 32 + quad * 8;
      f16x8 da[2];
      da[0] = *(const f16x8*)&Bh[(wave * 32 + m) * LSTR + ko];
      da[1] = *(const f16x8*)&Bh[(wave * 32 + 16 + m) * LSTR + ko];
#pragma unroll
      for (int lt = 0; lt < 4; ++lt) {
        f16x8 mb = *(const f16x8*)&Mt[(size_t)(lt * 16 + m) * N + C0 + ks * 32 + quad * 8];
        sacc[0][lt] = __builtin_amdgcn_mfma_f32_16x16x32_f16(da[0], mb, sacc[0][lt], 0, 0, 0);
        sacc[1][lt] = __builtin_amdgcn_mfma_f32_16x16x32_f16(da[1], mb, sacc[1][lt], 0, 0, 0);
      }
    }
  }

  // flush: one atomic per S entry (only col-split blocks contend per row)
#pragma unroll
  for (int rt = 0; rt < 2; ++rt)
#pragma unroll
    for (int lt = 0; lt < 4; ++lt)
#pragma unroll
      for (int r = 0; r < 4; ++r) {
        int row = wave * 32 + rt * 16 + quad * 4 + r;
        atomicAdd(&S[(size_t)(R + row) * NC + lt * 16 + m], sacc[rt][lt][r]);
      }
}

// ---------------- score: a, b, silhouette, mean ----------------
__global__ void score_kernel(const float* __restrict__ S,
                             const int* __restrict__ labels,
                             const int* __restrict__ counts,
                             float* __restrict__ out, int N) {
  __shared__ float cnt_s[NC];
  __shared__ float red[256];
  int t = threadIdx.x;
  if (t < NC) cnt_s[t] = (float)counts[t];
  __syncthreads();
  int i = blockIdx.x * 256 + t;
  float score = 0.f;
  if (i < N) {
    int li = labels[i];
    float own = cnt_s[li];
    const float* Si = S + (size_t)i * NC;
    float a = Si[li] / fmaxf(own - 1.f, 1.f);
    float b = FLT_MAX;
#pragma unroll
    for (int c = 0; c < NC; ++c) {
      float mm = Si[c] / fmaxf(cnt_s[c], 1.f);
      bool invalid = (c == li) || (cnt_s[c] == 0.f);
      b = fminf(b, invalid ? FLT_MAX : mm);
    }
    float mx = fmaxf(a, b);
    score = (own > 1.f) ? (b - a) / mx : 0.f;
  }
  red[t] = score;
  __syncthreads();
  for (int sft = 128; sft > 0; sft >>= 1) {
    if (t < sft) red[t] += red[t + sft];
    __syncthreads();
  }
  if (t == 0) atomicAdd(out, red[0] / (float)N);
}

extern "C" void kernel_launch(void* const* d_in, const int* in_sizes, int n_in,
                              void* d_out, int out_size, void* d_ws, size_t ws_size,
                              hipStream_t stream) {
  const float* feat = (const float*)d_in[0];
  const int* labels = (const int*)d_in[1];
  const int N = in_sizes[1];            // 8192; D=128, C=64 fixed by the reference
  float* out = (float*)d_out;
  char* ws = (char*)d_ws;

  // ws: counts(256B) | sq(N*4) | Xh(N*128*2) | Mt(64*N*2) | S(N*64*4)  ~5.03 MB @8192
  int*   counts = (int*)ws;
  float* sq     = (float*)(ws + 256);
  size_t o = 256 + (size_t)N * 4;
  o = (o + 255) & ~(size_t)255;
  unsigned short* Xh = (unsigned short*)(ws + o);                       // N*FD*2
  unsigned short* Mt = (unsigned short*)(ws + o + (size_t)N * FD * 2);  // NC*N*2
  float* S = (float*)(ws + o + (size_t)N * FD * 2 + (size_t)NC * N * 2);

  hipMemsetAsync(counts, 0, 256, stream);
  hipMemsetAsync(d_out, 0, (size_t)out_size * sizeof(float), stream);

  prep_kernel<<<(N + 31) / 32, 256, 0, stream>>>(feat, labels, sq, Xh, Mt, S, counts, N);

  const int colSplit = 8;               // 64 x 8 = 512 blocks = 2/CU (4 waves each)
  dim3 grid(N / 128, colSplit);
  mfma_tile_kernel<<<grid, 256, 0, stream>>>(Xh, sq, Mt, S, N, N / colSplit);

  score_kernel<<<(N + 255) / 256, 256, 0, stream>>>(S, labels, counts, out, N);
}

// Round 7
// 125.335 us; speedup vs baseline: 5.2568x; 1.3852x over previous
//
#include <hip/hip_runtime.h>
#include <hip/hip_fp16.h>
#include <float.h>

#define NC 64     // clusters
#define FD 128    // feature dim
#define LSTR 136  // LDS row stride in halfs (pad 16B)

typedef _Float16 f16x8 __attribute__((ext_vector_type(8)));
typedef float f32x4 __attribute__((ext_vector_type(4)));

// ---------------- prep: fp16 cast, |x|^2, histogram, Mt build, S zero, out zero ----
__global__ void prep_kernel(const float* __restrict__ feat,
                            const int* __restrict__ labels,
                            float* __restrict__ sq,
                            unsigned short* __restrict__ Xh,
                            unsigned short* __restrict__ Mt,
                            float* __restrict__ S,
                            float* __restrict__ out, int out_size,
                            int* __restrict__ counts, int N) {
  __shared__ int hist[NC];
  int t = threadIdx.x;
  if (t < NC) hist[t] = 0;
  __syncthreads();
  int row = blockIdx.x * 32 + (t >> 3);
  int o = t & 7;
  if (row < N) {
    const float* rp = feat + (size_t)row * FD;
    float s = 0.f;
#pragma unroll
    for (int j = 0; j < 4; ++j) {
      int c4 = o + 8 * j;
      float4 v = *(const float4*)(rp + c4 * 4);
      ushort4 h;
      h.x = __half_as_ushort(__float2half(v.x));   // RNE
      h.y = __half_as_ushort(__float2half(v.y));
      h.z = __half_as_ushort(__float2half(v.z));
      h.w = __half_as_ushort(__float2half(v.w));
      *(ushort4*)&Xh[(size_t)row * FD + c4 * 4] = h;
      s = fmaf(v.x, v.x, s); s = fmaf(v.y, v.y, s);
      s = fmaf(v.z, v.z, s); s = fmaf(v.w, v.w, s);
    }
    s += __shfl_xor(s, 1); s += __shfl_xor(s, 2); s += __shfl_xor(s, 4);
    if (o == 0) { sq[row] = s; atomicAdd(&hist[labels[row]], 1); }
  }
  // zero S rows for this block (32 rows x NC floats = 8 floats/thread)
  if ((blockIdx.x + 1) * 32 <= N) {
    float4 z = {0.f, 0.f, 0.f, 0.f};
    size_t base = (size_t)blockIdx.x * 32 * NC + t * 8;
    *(float4*)&S[base] = z;
    *(float4*)&S[base + 4] = z;
  }
  if (blockIdx.x == 0 && t < out_size) out[t] = 0.f;
  // build Mt[n][col] = (labels[col]==n) ? 1.0h : 0  (8-col chunks)
  {
    int chunksPerN = N >> 3;
    int total = NC * chunksPerN;
    for (int id = blockIdx.x * 256 + t; id < total; id += gridDim.x * 256) {
      int n = id / chunksPerN;
      int c0 = (id - n * chunksPerN) * 8;
      ushort4 lo, hi;
      lo.x = (labels[c0 + 0] == n) ? 0x3C00 : 0;
      lo.y = (labels[c0 + 1] == n) ? 0x3C00 : 0;
      lo.z = (labels[c0 + 2] == n) ? 0x3C00 : 0;
      lo.w = (labels[c0 + 3] == n) ? 0x3C00 : 0;
      hi.x = (labels[c0 + 4] == n) ? 0x3C00 : 0;
      hi.y = (labels[c0 + 5] == n) ? 0x3C00 : 0;
      hi.z = (labels[c0 + 6] == n) ? 0x3C00 : 0;
      hi.w = (labels[c0 + 7] == n) ? 0x3C00 : 0;
      *(ushort4*)&Mt[(size_t)n * N + c0] = lo;
      *(ushort4*)&Mt[(size_t)n * N + c0 + 4] = hi;
    }
  }
  __syncthreads();
  if (t < NC) atomicAdd(&counts[t], hist[t]);
}

// ---------------- main: fp16 MFMA Gram (operand-swapped) + MFMA segment-sum -------
// 256 threads = 4 waves in 2x2 grid, 64x64 wave tiles over a 128x128 block tile.
// Dist MFMA issued as mfma(B_cols, A_rows): output fragment is TRANSPOSED, so each
// lane holds 1 row x 4 contiguous cols -> packed cvt + ds_write_b64, and D lands
// row-major, which is exactly the S-pass A-operand layout. Bh reused as D.
// One-hot M frags stream from global Mt (L1/L2-resident) on the idle VMEM pipe.
__global__ __launch_bounds__(256, 2)
void mfma_tile_kernel(const unsigned short* __restrict__ Xh,
                      const float* __restrict__ sq,
                      const unsigned short* __restrict__ Mt,
                      float* __restrict__ S,
                      int N, int colsPerSplit) {
  __shared__ __align__(16) unsigned short Ah[128 * LSTR];  // 34816 B
  __shared__ __align__(16) unsigned short Bh[128 * LSTR];  // 34816 B, reused as D

  const int t = threadIdx.x;
  const int R = blockIdx.x * 128;
  const int cBeg = blockIdx.y * colsPerSplit;
  const int wave = t >> 6, lane = t & 63;
  const int mm = lane & 15, quad = lane >> 4;
  const int wr = wave >> 1, wc = wave & 1;   // 2x2 wave grid

  // stage A full-K: 2048 x 16B chunks over 256 threads
#pragma unroll
  for (int it = 0; it < 8; ++it) {
    int c = t + it * 256;
    int r = c >> 4, k0 = (c & 15) * 8;
    *(uint4*)&Ah[r * LSTR + k0] = *(const uint4*)&Xh[(size_t)(R + r) * FD + k0];
  }
  // per-lane row |x|^2: with transposed output, row = lane&15 within each ib tile
  float sqi_r[4];
#pragma unroll
  for (int ib = 0; ib < 4; ++ib)
    sqi_r[ib] = sq[R + wr * 64 + ib * 16 + mm];

  f32x4 sacc[2][4];                          // S accum: 2 row-tiles x 4 label-tiles
#pragma unroll
  for (int rt = 0; rt < 2; ++rt)
#pragma unroll
    for (int lt = 0; lt < 4; ++lt) sacc[rt][lt] = (f32x4)0.f;

  const int numTiles = colsPerSplit / 128;
  for (int ct = 0; ct < numTiles; ++ct) {
    const int C0 = cBeg + ct * 128;
    __syncthreads();                         // prev S-pass done before Bh overwrite
#pragma unroll
    for (int it = 0; it < 8; ++it) {
      int c = t + it * 256;
      int r = c >> 4, k0 = (c & 15) * 8;
      *(uint4*)&Bh[r * LSTR + k0] = *(const uint4*)&Xh[(size_t)(C0 + r) * FD + k0];
    }
    // col |x|^2: cols = quad*4 + r within each jb tile (transposed output layout)
    float sjr[4][4];
#pragma unroll
    for (int jb = 0; jb < 4; ++jb)
#pragma unroll
      for (int r = 0; r < 4; ++r)
        sjr[jb][r] = sq[C0 + wc * 64 + jb * 16 + quad * 4 + r];
    __syncthreads();

    // Dist pass: operands swapped -> transposed C/D fragments
    f32x4 dacc[4][4];                        // [ib][jb]
#pragma unroll
    for (int ib = 0; ib < 4; ++ib)
#pragma unroll
      for (int jb = 0; jb < 4; ++jb) dacc[ib][jb] = (f32x4)0.f;

#pragma unroll
    for (int ks = 0; ks < 4; ++ks) {
      const int ko = ks * 32 + quad * 8;
      f16x8 af[4], bf[4];
#pragma unroll
      for (int ib = 0; ib < 4; ++ib)
        af[ib] = *(const f16x8*)&Ah[(wr * 64 + ib * 16 + mm) * LSTR + ko];
#pragma unroll
      for (int jb = 0; jb < 4; ++jb)
        bf[jb] = *(const f16x8*)&Bh[(wc * 64 + jb * 16 + mm) * LSTR + ko];
#pragma unroll
      for (int ib = 0; ib < 4; ++ib)
#pragma unroll
        for (int jb = 0; jb < 4; ++jb)
          dacc[ib][jb] = __builtin_amdgcn_mfma_f32_16x16x32_f16(bf[jb], af[ib], dacc[ib][jb], 0, 0, 0);
    }
    __syncthreads();                         // all waves done reading Bh -> reuse as D

    // epilogue: lane holds row (lane&15), 4 contiguous cols (quad*4+r)
    const bool hasDiag = (R == C0);
#pragma unroll
    for (int ib = 0; ib < 4; ++ib) {
      const int rowLocal = wr * 64 + ib * 16 + mm;
      const float si = sqi_r[ib];
#pragma unroll
      for (int jb = 0; jb < 4; ++jb) {
        const int colBase = wc * 64 + jb * 16 + quad * 4;
        float d[4];
#pragma unroll
        for (int r = 0; r < 4; ++r) {
          float d2 = fmaf(-2.f, dacc[ib][jb][r], si + sjr[jb][r]);
          d[r] = __builtin_amdgcn_sqrtf(fmaxf(d2, 0.f));  // sqrt(0)=0: grad-safe
        }
        if (hasDiag) {                       // wave-uniform; 1 of numTiles iterations
#pragma unroll
          for (int r = 0; r < 4; ++r)
            if (rowLocal == colBase + r) d[r] = 0.f;
        }
        uint2 pk;
        pk.x = __builtin_bit_cast(unsigned, __builtin_amdgcn_cvt_pkrtz(d[0], d[1]));
        pk.y = __builtin_bit_cast(unsigned, __builtin_amdgcn_cvt_pkrtz(d[2], d[3]));
        *(uint2*)&Bh[rowLocal * LSTR + colBase] = pk;    // 8B store, aligned
      }
    }
    __syncthreads();                         // D ready

    // S-pass: S_tile[128xNC] += D[128x128] x M[128xNC]; M frags from global Mt
#pragma unroll
    for (int ks = 0; ks < 4; ++ks) {
      const int ko = ks * 32 + quad * 8;
      f16x8 da0 = *(const f16x8*)&Bh[(wave * 32 + mm) * LSTR + ko];
      f16x8 da1 = *(const f16x8*)&Bh[(wave * 32 + 16 + mm) * LSTR + ko];
#pragma unroll
      for (int lt = 0; lt < 4; ++lt) {
        f16x8 mb = *(const f16x8*)&Mt[(size_t)(lt * 16 + mm) * N + C0 + ks * 32 + quad * 8];
        sacc[0][lt] = __builtin_amdgcn_mfma_f32_16x16x32_f16(da0, mb, sacc[0][lt], 0, 0, 0);
        sacc[1][lt] = __builtin_amdgcn_mfma_f32_16x16x32_f16(da1, mb, sacc[1][lt], 0, 0, 0);
      }
    }
  }

  // flush: one atomic per S entry (only colSplit blocks contend per row)
#pragma unroll
  for (int rt = 0; rt < 2; ++rt)
#pragma unroll
    for (int lt = 0; lt < 4; ++lt)
#pragma unroll
      for (int r = 0; r < 4; ++r) {
        int row = wave * 32 + rt * 16 + quad * 4 + r;
        atomicAdd(&S[(size_t)(R + row) * NC + lt * 16 + mm], sacc[rt][lt][r]);
      }
}

// ---------------- score: a, b, silhouette, mean (vectorized) ----------------
__global__ void score_kernel(const float* __restrict__ S,
                             const int* __restrict__ labels,
                             const int* __restrict__ counts,
                             float* __restrict__ out, int N) {
  __shared__ float cnt_s[NC];
  __shared__ float inv_s[NC];
  __shared__ float red[128];
  int t = threadIdx.x;
  if (t < NC) {
    float c = (float)counts[t];
    cnt_s[t] = c;
    inv_s[t] = 1.f / fmaxf(c, 1.f);
  }
  __syncthreads();
  int i = blockIdx.x * 128 + t;
  float score = 0.f;
  if (i < N) {
    int li = labels[i];
    float own = cnt_s[li];
    const float4* Sv = (const float4*)(S + (size_t)i * NC);
    float a = S[(size_t)i * NC + li] / fmaxf(own - 1.f, 1.f);
    float b = FLT_MAX;
#pragma unroll
    for (int c4 = 0; c4 < NC / 4; ++c4) {
      float4 v = Sv[c4];
      int c = c4 * 4;
      float m0 = v.x * inv_s[c + 0];
      float m1 = v.y * inv_s[c + 1];
      float m2 = v.z * inv_s[c + 2];
      float m3 = v.w * inv_s[c + 3];
      b = fminf(b, (c + 0 == li || cnt_s[c + 0] == 0.f) ? FLT_MAX : m0);
      b = fminf(b, (c + 1 == li || cnt_s[c + 1] == 0.f) ? FLT_MAX : m1);
      b = fminf(b, (c + 2 == li || cnt_s[c + 2] == 0.f) ? FLT_MAX : m2);
      b = fminf(b, (c + 3 == li || cnt_s[c + 3] == 0.f) ? FLT_MAX : m3);
    }
    float mx = fmaxf(a, b);
    score = (own > 1.f) ? (b - a) / mx : 0.f;
  }
  red[t] = score;
  __syncthreads();
  for (int sft = 64; sft > 0; sft >>= 1) {
    if (t < sft) red[t] += red[t + sft];
    __syncthreads();
  }
  if (t == 0) atomicAdd(out, red[0] / (float)N);
}

extern "C" void kernel_launch(void* const* d_in, const int* in_sizes, int n_in,
                              void* d_out, int out_size, void* d_ws, size_t ws_size,
                              hipStream_t stream) {
  const float* feat = (const float*)d_in[0];
  const int* labels = (const int*)d_in[1];
  const int N = in_sizes[1];            // 8192; D=128, C=64 fixed by the reference
  float* out = (float*)d_out;
  char* ws = (char*)d_ws;

  // ws: counts(256B) | sq(N*4) | Xh(N*128*2) | Mt(64*N*2) | S(N*64*4)  ~5.03 MB @8192
  int*   counts = (int*)ws;
  float* sq     = (float*)(ws + 256);
  size_t o = 256 + (size_t)N * 4;
  o = (o + 255) & ~(size_t)255;
  unsigned short* Xh = (unsigned short*)(ws + o);                       // N*FD*2
  unsigned short* Mt = (unsigned short*)(ws + o + (size_t)N * FD * 2);  // NC*N*2
  float* S = (float*)(ws + o + (size_t)N * FD * 2 + (size_t)NC * N * 2);

  (void)hipMemsetAsync(counts, 0, 256, stream);

  prep_kernel<<<(N + 31) / 32, 256, 0, stream>>>(feat, labels, sq, Xh, Mt, S,
                                                 out, out_size, counts, N);

  const int colSplit = 8;               // 64 x 8 = 512 blocks = 2/CU (4 waves each)
  dim3 grid(N / 128, colSplit);
  mfma_tile_kernel<<<grid, 256, 0, stream>>>(Xh, sq, Mt, S, N, N / colSplit);

  score_kernel<<<(N + 127) / 128, 128, 0, stream>>>(S, labels, counts, out, N);
}